// Round 2
// baseline (108.304 us; speedup 1.0000x reference)
//
#include <hip/hip_runtime.h>

// ---------------------------------------------------------------------------
// Causal self-attention, B=4 T=4096 H=1024 D=64, fp32 in/out, bf16 MFMA inside.
// Pipeline: prep (weights->bf16) -> qkv GEMM -> fused flash-attention + out-proj.
// ws usage: 6.5 MiB (Wall 384K | Wo_b 128K | q 2M | k 2M | v 2M).
// ---------------------------------------------------------------------------

typedef __attribute__((ext_vector_type(4)))  float f32x4;
typedef __attribute__((ext_vector_type(16))) float f32x16;
typedef __attribute__((ext_vector_type(8)))  short s16x8;
typedef __attribute__((ext_vector_type(4)))  short s16x4;

#define DEV static __device__ __forceinline__

static constexpr int TT = 4096;        // sequence length
static constexpr int HH = 1024;        // hidden
static constexpr int DD = 64;          // head dim

DEV unsigned short f2bf(float f) {     // round-to-nearest-even fp32->bf16
  union { float f; unsigned int u; } v; v.f = f;
  unsigned int r = v.u + 0x7FFFu + ((v.u >> 16) & 1u);
  return (unsigned short)(r >> 16);
}

// XOR swizzles for 128B-row LDS tiles (bank-conflict avoidance)
DEV int swzA(int row) { return ((row & 7) << 4); }                     // 16-row tiles
DEV int swzK(int row) { return ((row & 7) << 4) ^ ((row & 8) << 3); }  // 32-row tiles
DEV int swzV(int d)   { return ((d & 7) << 4) ^ ((d & 24) << 2); }     // V^T tile

// ---------------------------------------------------------------------------
// Kernel 0: weights fp32 -> bf16.  Wall rows: [0,64)=Wq [64,128)=Wk [128,192)=Wv
// ---------------------------------------------------------------------------
__global__ void prep_kernel(const float* __restrict__ Wq, const float* __restrict__ Wk,
                            const float* __restrict__ Wv, const float* __restrict__ Wo,
                            unsigned short* __restrict__ Wall,
                            unsigned short* __restrict__ Wo_b)
{
  int i = blockIdx.x * blockDim.x + threadIdx.x;
  int stride = gridDim.x * blockDim.x;
  const int n1 = 64 * HH;
  for (int idx = i; idx < 3 * n1; idx += stride) {
    float v = idx < n1 ? Wq[idx] : (idx < 2 * n1 ? Wk[idx - n1] : Wv[idx - 2 * n1]);
    Wall[idx] = f2bf(v);
  }
  for (int idx = i; idx < HH * DD; idx += stride) Wo_b[idx] = f2bf(Wo[idx]);
}

// ---------------------------------------------------------------------------
// Kernel 1: QKV projection.  q/k/v[bt][64] bf16, q pre-scaled by log2e/8.
// 256 blocks x 256 thr; block = 64 rows x 192 cols; K=1024 in 16 steps of 64.
// Double-buffered LDS; next-step global loads issued before current compute.
// ---------------------------------------------------------------------------
__global__ __launch_bounds__(256) void qkv_kernel(
    const float* __restrict__ y, const unsigned short* __restrict__ Wall,
    const float* __restrict__ bq, const float* __restrict__ bk,
    const float* __restrict__ bv,
    unsigned short* __restrict__ q_ws, unsigned short* __restrict__ k_ws,
    unsigned short* __restrict__ v_ws)
{
  __shared__ unsigned short ylds[2][64 * 64];
  __shared__ unsigned short wlds[2][192 * 64];
  const int t = threadIdx.x;
  const int w = t >> 6, lane = t & 63, g = lane >> 4, c = lane & 15;
  const int row0 = blockIdx.x * 64;
  const int yrow = t >> 2, ycol0 = (t & 3) * 16;

  f32x4 acc[12];
#pragma unroll
  for (int i = 0; i < 12; ++i)
#pragma unroll
    for (int e = 0; e < 4; ++e) acc[i][e] = 0.0f;

  f32x4 yr[4];
  s16x8 wr[6];

  auto load_tiles = [&](int kb) {
    const float* src = y + (size_t)(row0 + yrow) * HH + kb * 64 + ycol0;
    yr[0] = *(const f32x4*)(src);
    yr[1] = *(const f32x4*)(src + 4);
    yr[2] = *(const f32x4*)(src + 8);
    yr[3] = *(const f32x4*)(src + 12);
#pragma unroll
    for (int ii = 0; ii < 6; ++ii) {
      int ch = t + ii * 256;
      int rw = ch >> 3, c0 = (ch & 7) * 8;
      wr[ii] = *(const s16x8*)(Wall + (size_t)rw * HH + kb * 64 + c0);
    }
  };
  auto write_tiles = [&](int buf) {
    s16x8 h0, h1;
#pragma unroll
    for (int e = 0; e < 4; ++e) {
      h0[e]     = (short)f2bf(yr[0][e]);
      h0[e + 4] = (short)f2bf(yr[1][e]);
      h1[e]     = (short)f2bf(yr[2][e]);
      h1[e + 4] = (short)f2bf(yr[3][e]);
    }
    int byte0 = yrow * 128 + ycol0 * 2;
    *(s16x8*)((char*)ylds[buf] + (byte0 ^ swzA(yrow)))        = h0;
    *(s16x8*)((char*)ylds[buf] + ((byte0 + 16) ^ swzA(yrow))) = h1;
#pragma unroll
    for (int ii = 0; ii < 6; ++ii) {
      int ch = t + ii * 256;
      int rw = ch >> 3, c0 = (ch & 7) * 8;
      int byte = rw * 128 + c0 * 2;
      *(s16x8*)((char*)wlds[buf] + (byte ^ swzA(rw))) = wr[ii];
    }
  };

  load_tiles(0);
  write_tiles(0);
  __syncthreads();
  for (int kb = 0; kb < 16; ++kb) {
    int buf = kb & 1;
    if (kb < 15) load_tiles(kb + 1);
#pragma unroll
    for (int kk = 0; kk < 2; ++kk) {
      int r = 16 * w + c;
      s16x8 a = *(const s16x8*)((char*)ylds[buf] +
                  ((r * 128 + (kk * 32 + 8 * g) * 2) ^ swzA(r)));
#pragma unroll
      for (int nt = 0; nt < 12; ++nt) {
        int rb = 16 * nt + c;
        s16x8 b = *(const s16x8*)((char*)wlds[buf] +
                    ((rb * 128 + (kk * 32 + 8 * g) * 2) ^ swzA(rb)));
        acc[nt] = __builtin_amdgcn_mfma_f32_16x16x32_bf16(a, b, acc[nt], 0, 0, 0);
      }
    }
    __syncthreads();
    if (kb < 15) { write_tiles((kb + 1) & 1); __syncthreads(); }
  }

  const float qsc = 1.4426950408889634f / 8.0f;   // log2e / sqrt(Dk)
#pragma unroll
  for (int nt = 0; nt < 12; ++nt) {
    int col = 16 * nt + c;
    int sec = nt >> 2;
    int dcol = col & 63;
    float bias = sec == 0 ? bq[dcol] : (sec == 1 ? bk[dcol] : bv[dcol]);
    unsigned short* dst = sec == 0 ? q_ws : (sec == 1 ? k_ws : v_ws);
#pragma unroll
    for (int i = 0; i < 4; ++i) {
      int row = row0 + 16 * w + 4 * g + i;
      float val = acc[nt][i] + bias;
      if (sec == 0) val *= qsc;
      dst[(size_t)row * DD + dcol] = f2bf(val);
    }
  }
}

// ---------------------------------------------------------------------------
// Kernel 2: fused flash attention + output projection.
// Grid 256 = 4 batches x 64 q-tiles(64 rows). 4 waves = 2 qsub x 2 kv-parity.
// S^T = K.Q^T (32x32x16, q=lane&31 -> per-lane row softmax, shfl_xor(32)).
// PV as O^T = V^T.P^T.  Staging software-pipelined (loads issued 1 rnd early).
// After flash merge: ctx -> LDS (bf16), block GEMM 64x1024 vs Wo^T + bias -> out.
// ---------------------------------------------------------------------------
__global__ __launch_bounds__(256) void attn_kernel(
    const unsigned short* __restrict__ q_ws, const unsigned short* __restrict__ k_ws,
    const unsigned short* __restrict__ v_ws, const unsigned short* __restrict__ Wo_b,
    const float* __restrict__ bo, float* __restrict__ out)
{
  __shared__ unsigned short klds[2][64 * 64];   // [parity][kv][d] swizzled swzK
  __shared__ unsigned short vlds[2][64 * 64];   // [parity][d][kv] (V^T) swizzled swzV
  __shared__ unsigned short plds[4][32 * 64];   // per-wave P^T [q][kv] swzK; later ctx
  const int t = threadIdx.x, wv = t >> 6, lane = t & 63;
  const int qsub = wv & 1, kvh = wv >> 1;
  const int qcol = lane & 31, h = lane >> 5;
  const int b = blockIdx.x >> 6, jq = blockIdx.x & 63;
  const int q0 = jq * 64;
  const size_t base = (size_t)b * TT * DD;
  const int g = lane >> 4, c = lane & 15;       // for the proj phase

  // Q fragments (B-operand): lane holds Q[q0+32*qsub+qcol][16*kk+8*h + j]
  s16x8 qf[4];
  {
    const unsigned short* qp = q_ws + base + (size_t)(q0 + 32 * qsub + qcol) * DD + 8 * h;
#pragma unroll
    for (int kk = 0; kk < 4; ++kk) qf[kk] = *(const s16x8*)(qp + 16 * kk);
  }
  f32x16 o[2];
#pragma unroll
  for (int mt = 0; mt < 2; ++mt)
#pragma unroll
    for (int rg = 0; rg < 16; ++rg) o[mt][rg] = 0.0f;
  float m_run = -__builtin_inff(), l_run = 0.0f;

  // staging registers (software pipeline, 1 round ahead)
  const int kv_a = t >> 3, d0s = (t & 7) * 8;   // K chunks & V rows assignment
  s16x8 kreg[2][2], v0reg[2], v1reg[2];

  auto issue_loads = [&](int r) {
#pragma unroll
    for (int tile = 0; tile < 2; ++tile) {
      int kt = 2 * r + tile;
      if (kt <= jq) {                            // block-uniform condition
        int kv0 = kt * 64;
        kreg[tile][0] = *(const s16x8*)(k_ws + base + (size_t)(kv0 + kv_a) * DD + d0s);
        kreg[tile][1] = *(const s16x8*)(k_ws + base + (size_t)(kv0 + 32 + kv_a) * DD + d0s);
        const unsigned short* vp = v_ws + base + (size_t)(kv0 + 2 * kv_a) * DD + d0s;
        v0reg[tile] = *(const s16x8*)(vp);
        v1reg[tile] = *(const s16x8*)(vp + DD);
      }
    }
  };
  auto write_lds = [&](int r) {
#pragma unroll
    for (int tile = 0; tile < 2; ++tile) {
      int kt = 2 * r + tile;
      if (kt <= jq) {
        int byte = kv_a * 128 + d0s * 2;
        *(s16x8*)((char*)klds[tile] + (byte ^ swzK(kv_a))) = kreg[tile][0];
        int byte2 = (kv_a + 32) * 128 + d0s * 2;
        *(s16x8*)((char*)klds[tile] + (byte2 ^ swzK(kv_a + 32))) = kreg[tile][1];
#pragma unroll
        for (int j = 0; j < 8; ++j) {
          int d = d0s + j;
          unsigned int pair = (unsigned int)(unsigned short)v0reg[tile][j]
                            | ((unsigned int)(unsigned short)v1reg[tile][j] << 16);
          int vb = d * 128 + kv_a * 4;
          *(unsigned int*)((char*)vlds[tile] + (vb ^ swzV(d))) = pair;
        }
      }
    }
  };

  const int rounds = (jq >> 1) + 1;
  issue_loads(0);
  for (int r = 0; r < rounds; ++r) {
    __syncthreads();                 // prev compute done reading LDS
    write_lds(r);
    __syncthreads();                 // tiles visible
    if (r + 1 < rounds) issue_loads(r + 1);   // hidden under compute
    int kt = 2 * r + kvh;
    if (kt <= jq) {
      // ---- S^T = K . Q^T ----
      f32x16 s[2];
#pragma unroll
      for (int mt = 0; mt < 2; ++mt)
#pragma unroll
        for (int rg = 0; rg < 16; ++rg) s[mt][rg] = 0.0f;
#pragma unroll
      for (int kk = 0; kk < 4; ++kk) {
#pragma unroll
        for (int mt = 0; mt < 2; ++mt) {
          int kr = 32 * mt + qcol;
          s16x8 a = *(const s16x8*)((char*)klds[kvh] +
                      ((kr * 128 + (16 * kk + 8 * h) * 2) ^ swzK(kr)));
          s[mt] = __builtin_amdgcn_mfma_f32_32x32x16_bf16(a, qf[kk], s[mt], 0, 0, 0);
        }
      }
      if (kt == jq) {                // causal mask, diagonal tile
        int qq = 32 * qsub + qcol;
#pragma unroll
        for (int mt = 0; mt < 2; ++mt)
#pragma unroll
          for (int rg = 0; rg < 16; ++rg) {
            int kvloc = 32 * mt + (rg & 3) + 8 * (rg >> 2) + 4 * h;
            if (kvloc > qq) s[mt][rg] = -__builtin_inff();
          }
      }
      // ---- online softmax (log2 domain) ----
      float pm = -__builtin_inff();
#pragma unroll
      for (int mt = 0; mt < 2; ++mt)
#pragma unroll
        for (int rg = 0; rg < 16; ++rg) pm = fmaxf(pm, s[mt][rg]);
      pm = fmaxf(pm, __shfl_xor(pm, 32));
      float m_new = fmaxf(m_run, pm);
      float alpha = exp2f(m_run - m_new);
      float rowsum = 0.0f;
#pragma unroll
      for (int mt = 0; mt < 2; ++mt) {
#pragma unroll
        for (int r2 = 0; r2 < 4; ++r2) {
          s16x4 pb;
#pragma unroll
          for (int e = 0; e < 4; ++e) {
            float p = exp2f(s[mt][4 * r2 + e] - m_new);
            rowsum += p;
            pb[e] = (short)f2bf(p);
          }
          int kvb = 32 * mt + 8 * r2 + 4 * h;
          int byte = qcol * 128 + kvb * 2;
          *(s16x4*)((char*)plds[wv] + (byte ^ swzK(qcol))) = pb;
        }
      }
      rowsum += __shfl_xor(rowsum, 32);
      l_run = l_run * alpha + rowsum;
      m_run = m_new;
#pragma unroll
      for (int mt = 0; mt < 2; ++mt)
#pragma unroll
        for (int rg = 0; rg < 16; ++rg) o[mt][rg] *= alpha;
      // ---- O^T += V^T . P^T ----
#pragma unroll
      for (int kk = 0; kk < 4; ++kk) {
        s16x8 pbf = *(const s16x8*)((char*)plds[wv] +
                      ((qcol * 128 + (16 * kk + 8 * h) * 2) ^ swzK(qcol)));
#pragma unroll
        for (int mt = 0; mt < 2; ++mt) {
          int dr = 32 * mt + qcol;
          s16x8 vbr = *(const s16x8*)((char*)vlds[kvh] +
                        ((dr * 128 + (16 * kk + 8 * h) * 2) ^ swzV(dr)));
          o[mt] = __builtin_amdgcn_mfma_f32_32x32x16_bf16(vbr, pbf, o[mt], 0, 0, 0);
        }
      }
    }
  }

  // ---- merge kv-parity halves; ctx -> LDS (bf16, [q][d], swzK rows) ----
  __syncthreads();
  float* obuf  = (float*)klds;      // 4096 floats (all of klds) — dead now
  float* mstat = (float*)vlds;      // 256 floats — dead now
  unsigned short* clds = &plds[0][0];  // ctx tile, 8 KB of plds — dead now
  if (kvh == 1) {
#pragma unroll
    for (int mt = 0; mt < 2; ++mt)
#pragma unroll
      for (int rg = 0; rg < 16; ++rg)
        obuf[qsub * 2048 + (mt * 16 + rg) * 64 + lane] = o[mt][rg];
    mstat[qsub * 128 + lane] = m_run;
    mstat[qsub * 128 + 64 + lane] = l_run;
  }
  __syncthreads();
  if (kvh == 0) {
    float mB = mstat[qsub * 128 + lane];
    float lB = mstat[qsub * 128 + 64 + lane];
    float mS = fmaxf(m_run, mB);
    float fA = exp2f(m_run - mS), fB = exp2f(mB - mS);
    float inv = 1.0f / (l_run * fA + lB * fB);
    int qrl = 32 * qsub + qcol;
#pragma unroll
    for (int mt = 0; mt < 2; ++mt) {
#pragma unroll
      for (int rgq = 0; rgq < 4; ++rgq) {
        s16x4 pb;
#pragma unroll
        for (int e = 0; e < 4; ++e) {
          int rg = 4 * rgq + e;
          float val = (o[mt][rg] * fA +
                       obuf[qsub * 2048 + (mt * 16 + rg) * 64 + lane] * fB) * inv;
          pb[e] = (short)f2bf(val);
        }
        int d0 = 32 * mt + 8 * rgq + 4 * h;
        int byte = qrl * 128 + d0 * 2;
        *(s16x4*)((char*)clds + (byte ^ swzK(qrl))) = pb;
      }
    }
  }
  __syncthreads();

  // ---- fused output projection: out[q0..q0+64) x 1024 = ctx(64x64) . Wo^T ----
  // A-frags from clds (rows q, k=d); B-frags from Wo_b global (row=hcol, k=d).
  s16x8 afr[4][2];
#pragma unroll
  for (int mt = 0; mt < 4; ++mt)
#pragma unroll
    for (int kk = 0; kk < 2; ++kk) {
      int ra = 16 * mt + c;
      afr[mt][kk] = *(const s16x8*)((char*)clds +
                      ((ra * 128 + (32 * kk + 8 * g) * 2) ^ swzK(ra)));
    }
  const int n0w = wv * 256;
  const size_t orow0 = (size_t)(b * TT + q0);
#pragma unroll 4
  for (int nt = 0; nt < 16; ++nt) {
    int col = n0w + 16 * nt + c;
    s16x8 bfr[2];
#pragma unroll
    for (int kk = 0; kk < 2; ++kk)
      bfr[kk] = *(const s16x8*)(Wo_b + (size_t)col * DD + 32 * kk + 8 * g);
    f32x4 acc4[4];
#pragma unroll
    for (int mt = 0; mt < 4; ++mt)
#pragma unroll
      for (int e = 0; e < 4; ++e) acc4[mt][e] = 0.0f;
#pragma unroll
    for (int kk = 0; kk < 2; ++kk)
#pragma unroll
      for (int mt = 0; mt < 4; ++mt)
        acc4[mt] = __builtin_amdgcn_mfma_f32_16x16x32_bf16(afr[mt][kk], bfr[kk],
                                                           acc4[mt], 0, 0, 0);
    float bias = bo[col];
#pragma unroll
    for (int mt = 0; mt < 4; ++mt)
#pragma unroll
      for (int i = 0; i < 4; ++i) {
        size_t row = orow0 + 16 * mt + 4 * g + i;
        out[row * HH + col] = acc4[mt][i] + bias;
      }
  }
}

// ---------------------------------------------------------------------------
extern "C" void kernel_launch(void* const* d_in, const int* in_sizes, int n_in,
                              void* d_out, int out_size, void* d_ws, size_t ws_size,
                              hipStream_t stream)
{
  const float* y  = (const float*)d_in[0];
  const float* Wq = (const float*)d_in[1];
  const float* bq = (const float*)d_in[2];
  const float* Wk = (const float*)d_in[3];
  const float* bk = (const float*)d_in[4];
  const float* Wv = (const float*)d_in[5];
  const float* bv = (const float*)d_in[6];
  const float* Wo = (const float*)d_in[7];
  const float* bo = (const float*)d_in[8];
  float* out = (float*)d_out;
  char* ws = (char*)d_ws;
  // workspace layout (bytes) — total 6,815,744 (6.5 MiB)
  unsigned short* Wall = (unsigned short*)(ws);                        // 384 KiB
  unsigned short* Wo_b = (unsigned short*)(ws + 393216);               // 128 KiB
  unsigned short* q_ws = (unsigned short*)(ws + 524288);               // 2 MiB
  unsigned short* k_ws = (unsigned short*)(ws + 524288 + 2097152);     // 2 MiB
  unsigned short* v_ws = (unsigned short*)(ws + 524288 + 2 * 2097152); // 2 MiB

  prep_kernel<<<dim3(256), dim3(256), 0, stream>>>(Wq, Wk, Wv, Wo, Wall, Wo_b);
  qkv_kernel<<<dim3(256), dim3(256), 0, stream>>>(y, Wall, bq, bk, bv, q_ws, k_ws, v_ws);
  attn_kernel<<<dim3(256), dim3(256), 0, stream>>>(q_ws, k_ws, v_ws, Wo_b, bo, out);
}

// Round 3
// 98.353 us; speedup vs baseline: 1.1012x; 1.1012x over previous
//
#include <hip/hip_runtime.h>

// ---------------------------------------------------------------------------
// Causal self-attention, B=4 T=4096 H=1024 D=64, fp32 in/out, bf16 MFMA inside.
// Pipeline: prep (weights->bf16) -> qkv GEMM -> fused flash-attention + out-proj.
// ws usage: 6.5 MiB (Wall 384K | Wo_b 128K | q 2M | k 2M | v 2M).
// attn: 512 blocks (4 b x 128 q-tiles of 32 rows), 4 waves = 4-way KV parity,
// 2 blocks/CU (80 KiB LDS), heavy/light block interleave for balance.
// ---------------------------------------------------------------------------

typedef __attribute__((ext_vector_type(4)))  float f32x4;
typedef __attribute__((ext_vector_type(16))) float f32x16;
typedef __attribute__((ext_vector_type(8)))  short s16x8;
typedef __attribute__((ext_vector_type(4)))  short s16x4;

#define DEV static __device__ __forceinline__

static constexpr int TT = 4096;        // sequence length
static constexpr int HH = 1024;        // hidden
static constexpr int DD = 64;          // head dim

DEV unsigned short f2bf(float f) {     // round-to-nearest-even fp32->bf16
  union { float f; unsigned int u; } v; v.f = f;
  unsigned int r = v.u + 0x7FFFu + ((v.u >> 16) & 1u);
  return (unsigned short)(r >> 16);
}

// XOR swizzles for 128B-row LDS tiles (bank-conflict avoidance)
DEV int swzA(int row) { return ((row & 7) << 4); }                     // 16-row tiles
DEV int swzK(int row) { return ((row & 7) << 4) ^ ((row & 8) << 3); }  // 32-row tiles
DEV int swzV(int d)   { return ((d & 7) << 4) ^ ((d & 24) << 2); }     // V^T tile

// ---------------------------------------------------------------------------
// Kernel 0: weights fp32 -> bf16.  Wall rows: [0,64)=Wq [64,128)=Wk [128,192)=Wv
// ---------------------------------------------------------------------------
__global__ void prep_kernel(const float* __restrict__ Wq, const float* __restrict__ Wk,
                            const float* __restrict__ Wv, const float* __restrict__ Wo,
                            unsigned short* __restrict__ Wall,
                            unsigned short* __restrict__ Wo_b)
{
  int i = blockIdx.x * blockDim.x + threadIdx.x;
  int stride = gridDim.x * blockDim.x;
  const int n1 = 64 * HH;
  for (int idx = i; idx < 3 * n1; idx += stride) {
    float v = idx < n1 ? Wq[idx] : (idx < 2 * n1 ? Wk[idx - n1] : Wv[idx - 2 * n1]);
    Wall[idx] = f2bf(v);
  }
  for (int idx = i; idx < HH * DD; idx += stride) Wo_b[idx] = f2bf(Wo[idx]);
}

// ---------------------------------------------------------------------------
// Kernel 1: QKV projection.  q/k/v[bt][64] bf16, q pre-scaled by log2e/8.
// 256 blocks x 256 thr; block = 64 rows x 192 cols; K=1024 in 16 steps of 64.
// ---------------------------------------------------------------------------
__global__ __launch_bounds__(256) void qkv_kernel(
    const float* __restrict__ y, const unsigned short* __restrict__ Wall,
    const float* __restrict__ bq, const float* __restrict__ bk,
    const float* __restrict__ bv,
    unsigned short* __restrict__ q_ws, unsigned short* __restrict__ k_ws,
    unsigned short* __restrict__ v_ws)
{
  __shared__ unsigned short ylds[2][64 * 64];
  __shared__ unsigned short wlds[2][192 * 64];
  const int t = threadIdx.x;
  const int w = t >> 6, lane = t & 63, g = lane >> 4, c = lane & 15;
  const int row0 = blockIdx.x * 64;
  const int yrow = t >> 2, ycol0 = (t & 3) * 16;

  f32x4 acc[12];
#pragma unroll
  for (int i = 0; i < 12; ++i)
#pragma unroll
    for (int e = 0; e < 4; ++e) acc[i][e] = 0.0f;

  f32x4 yr[4];
  s16x8 wr[6];

  auto load_tiles = [&](int kb) {
    const float* src = y + (size_t)(row0 + yrow) * HH + kb * 64 + ycol0;
    yr[0] = *(const f32x4*)(src);
    yr[1] = *(const f32x4*)(src + 4);
    yr[2] = *(const f32x4*)(src + 8);
    yr[3] = *(const f32x4*)(src + 12);
#pragma unroll
    for (int ii = 0; ii < 6; ++ii) {
      int ch = t + ii * 256;
      int rw = ch >> 3, c0 = (ch & 7) * 8;
      wr[ii] = *(const s16x8*)(Wall + (size_t)rw * HH + kb * 64 + c0);
    }
  };
  auto write_tiles = [&](int buf) {
    s16x8 h0, h1;
#pragma unroll
    for (int e = 0; e < 4; ++e) {
      h0[e]     = (short)f2bf(yr[0][e]);
      h0[e + 4] = (short)f2bf(yr[1][e]);
      h1[e]     = (short)f2bf(yr[2][e]);
      h1[e + 4] = (short)f2bf(yr[3][e]);
    }
    int byte0 = yrow * 128 + ycol0 * 2;
    *(s16x8*)((char*)ylds[buf] + (byte0 ^ swzA(yrow)))        = h0;
    *(s16x8*)((char*)ylds[buf] + ((byte0 + 16) ^ swzA(yrow))) = h1;
#pragma unroll
    for (int ii = 0; ii < 6; ++ii) {
      int ch = t + ii * 256;
      int rw = ch >> 3, c0 = (ch & 7) * 8;
      int byte = rw * 128 + c0 * 2;
      *(s16x8*)((char*)wlds[buf] + (byte ^ swzA(rw))) = wr[ii];
    }
  };

  load_tiles(0);
  write_tiles(0);
  __syncthreads();
  for (int kb = 0; kb < 16; ++kb) {
    int buf = kb & 1;
    if (kb < 15) load_tiles(kb + 1);
#pragma unroll
    for (int kk = 0; kk < 2; ++kk) {
      int r = 16 * w + c;
      s16x8 a = *(const s16x8*)((char*)ylds[buf] +
                  ((r * 128 + (kk * 32 + 8 * g) * 2) ^ swzA(r)));
#pragma unroll
      for (int nt = 0; nt < 12; ++nt) {
        int rb = 16 * nt + c;
        s16x8 b = *(const s16x8*)((char*)wlds[buf] +
                    ((rb * 128 + (kk * 32 + 8 * g) * 2) ^ swzA(rb)));
        acc[nt] = __builtin_amdgcn_mfma_f32_16x16x32_bf16(a, b, acc[nt], 0, 0, 0);
      }
    }
    __syncthreads();
    if (kb < 15) { write_tiles((kb + 1) & 1); __syncthreads(); }
  }

  const float qsc = 1.4426950408889634f / 8.0f;   // log2e / sqrt(Dk)
#pragma unroll
  for (int nt = 0; nt < 12; ++nt) {
    int col = 16 * nt + c;
    int sec = nt >> 2;
    int dcol = col & 63;
    float bias = sec == 0 ? bq[dcol] : (sec == 1 ? bk[dcol] : bv[dcol]);
    unsigned short* dst = sec == 0 ? q_ws : (sec == 1 ? k_ws : v_ws);
#pragma unroll
    for (int i = 0; i < 4; ++i) {
      int row = row0 + 16 * w + 4 * g + i;
      float val = acc[nt][i] + bias;
      if (sec == 0) val *= qsc;
      dst[(size_t)row * DD + dcol] = f2bf(val);
    }
  }
}

// ---------------------------------------------------------------------------
// Kernel 2: fused flash attention + output projection.
// Grid 512 = 4 b x 128 q-tiles (32 rows), heavy/light interleaved.
// 4 waves = 4-way KV parity; round r stages KV tiles 4r..4r+3, wave w does 4r+w.
// S^T = K.Q^T (32x32x16, q=lane&31 -> per-lane row softmax, shfl_xor(32)).
// PV as O^T = V^T.P^T.  4-way flash merge in wave 0, then 32x1024 out-proj.
// ---------------------------------------------------------------------------
__global__ __launch_bounds__(256) void attn_kernel(
    const unsigned short* __restrict__ q_ws, const unsigned short* __restrict__ k_ws,
    const unsigned short* __restrict__ v_ws, const unsigned short* __restrict__ Wo_b,
    const float* __restrict__ bo, float* __restrict__ out)
{
  __shared__ unsigned short klds[4][64 * 64];   // [parity][kv][d]  swzK rows
  __shared__ unsigned short vlds[4][64 * 64];   // [parity][d][kv]  (V^T) swzV rows
  __shared__ unsigned short plds[4][32 * 64];   // per-wave P^T [q][kv] swzK; later ctx
  const int t = threadIdx.x, wv = t >> 6, lane = t & 63;
  const int qcol = lane & 31, h = lane >> 5;
  const int idx = blockIdx.x;
  const int b = idx & 3;
  const int jslot = idx >> 2;
  const int j32 = (jslot & 1) ? (127 - (jslot >> 1)) : (jslot >> 1);
  const int q0 = j32 * 32;
  const int L = j32 >> 1;               // last KV tile index (diagonal tile)
  const size_t base = (size_t)b * TT * DD;
  const int g = lane >> 4, c = lane & 15;       // for the proj phase

  // Q fragments (B-operand): lane holds Q[q0+qcol][16*kk+8*h + j]
  s16x8 qf[4];
  {
    const unsigned short* qp = q_ws + base + (size_t)(q0 + qcol) * DD + 8 * h;
#pragma unroll
    for (int kk = 0; kk < 4; ++kk) qf[kk] = *(const s16x8*)(qp + 16 * kk);
  }
  f32x16 o[2];
#pragma unroll
  for (int mt = 0; mt < 2; ++mt)
#pragma unroll
    for (int rg = 0; rg < 16; ++rg) o[mt][rg] = 0.0f;
  float m_run = -__builtin_inff(), l_run = 0.0f;

  // staging registers (software pipeline, 1 round ahead; 4 tiles per round)
  const int kv_a = t >> 3, d0s = (t & 7) * 8;
  s16x8 kreg[4][2], v0reg[4], v1reg[4];

  auto issue_loads = [&](int r) {
#pragma unroll
    for (int tile = 0; tile < 4; ++tile) {
      int kt = 4 * r + tile;
      if (kt <= L) {                     // block-uniform condition
        int kv0 = kt * 64;
        kreg[tile][0] = *(const s16x8*)(k_ws + base + (size_t)(kv0 + kv_a) * DD + d0s);
        kreg[tile][1] = *(const s16x8*)(k_ws + base + (size_t)(kv0 + 32 + kv_a) * DD + d0s);
        const unsigned short* vp = v_ws + base + (size_t)(kv0 + 2 * kv_a) * DD + d0s;
        v0reg[tile] = *(const s16x8*)(vp);
        v1reg[tile] = *(const s16x8*)(vp + DD);
      }
    }
  };
  auto write_lds = [&](int r) {
#pragma unroll
    for (int tile = 0; tile < 4; ++tile) {
      int kt = 4 * r + tile;
      if (kt <= L) {
        int byte = kv_a * 128 + d0s * 2;
        *(s16x8*)((char*)klds[tile] + (byte ^ swzK(kv_a))) = kreg[tile][0];
        int byte2 = (kv_a + 32) * 128 + d0s * 2;
        *(s16x8*)((char*)klds[tile] + (byte2 ^ swzK(kv_a + 32))) = kreg[tile][1];
#pragma unroll
        for (int j = 0; j < 8; ++j) {
          int d = d0s + j;
          unsigned int pair = (unsigned int)(unsigned short)v0reg[tile][j]
                            | ((unsigned int)(unsigned short)v1reg[tile][j] << 16);
          int vb = d * 128 + kv_a * 4;
          *(unsigned int*)((char*)vlds[tile] + (vb ^ swzV(d))) = pair;
        }
      }
    }
  };

  const int rounds = (L + 4) >> 2;
  issue_loads(0);
  for (int r = 0; r < rounds; ++r) {
    __syncthreads();                 // prev compute done reading LDS
    write_lds(r);
    __syncthreads();                 // tiles visible
    if (r + 1 < rounds) issue_loads(r + 1);   // hidden under compute
    int kt = 4 * r + wv;
    if (kt <= L) {
      // ---- S^T = K . Q^T ----
      f32x16 s[2];
#pragma unroll
      for (int mt = 0; mt < 2; ++mt)
#pragma unroll
        for (int rg = 0; rg < 16; ++rg) s[mt][rg] = 0.0f;
      __builtin_amdgcn_s_setprio(1);
#pragma unroll
      for (int kk = 0; kk < 4; ++kk) {
#pragma unroll
        for (int mt = 0; mt < 2; ++mt) {
          int kr = 32 * mt + qcol;
          s16x8 a = *(const s16x8*)((char*)klds[wv] +
                      ((kr * 128 + (16 * kk + 8 * h) * 2) ^ swzK(kr)));
          s[mt] = __builtin_amdgcn_mfma_f32_32x32x16_bf16(a, qf[kk], s[mt], 0, 0, 0);
        }
      }
      __builtin_amdgcn_s_setprio(0);
      if (kt == L) {                 // causal mask, diagonal tile
        int qq = q0 + qcol;
#pragma unroll
        for (int mt = 0; mt < 2; ++mt)
#pragma unroll
          for (int rg = 0; rg < 16; ++rg) {
            int kvabs = kt * 64 + 32 * mt + (rg & 3) + 8 * (rg >> 2) + 4 * h;
            if (kvabs > qq) s[mt][rg] = -__builtin_inff();
          }
      }
      // ---- online softmax (log2 domain) ----
      float pm = -__builtin_inff();
#pragma unroll
      for (int mt = 0; mt < 2; ++mt)
#pragma unroll
        for (int rg = 0; rg < 16; ++rg) pm = fmaxf(pm, s[mt][rg]);
      pm = fmaxf(pm, __shfl_xor(pm, 32));
      float m_new = fmaxf(m_run, pm);
      float alpha = exp2f(m_run - m_new);
      float rowsum = 0.0f;
#pragma unroll
      for (int mt = 0; mt < 2; ++mt) {
#pragma unroll
        for (int r2 = 0; r2 < 4; ++r2) {
          s16x4 pb;
#pragma unroll
          for (int e = 0; e < 4; ++e) {
            float p = exp2f(s[mt][4 * r2 + e] - m_new);
            rowsum += p;
            pb[e] = (short)f2bf(p);
          }
          int kvb = 32 * mt + 8 * r2 + 4 * h;
          int byte = qcol * 128 + kvb * 2;
          *(s16x4*)((char*)plds[wv] + (byte ^ swzK(qcol))) = pb;
        }
      }
      rowsum += __shfl_xor(rowsum, 32);
      l_run = l_run * alpha + rowsum;
      m_run = m_new;
#pragma unroll
      for (int mt = 0; mt < 2; ++mt)
#pragma unroll
        for (int rg = 0; rg < 16; ++rg) o[mt][rg] *= alpha;
      // ---- O^T += V^T . P^T ----
      __builtin_amdgcn_s_setprio(1);
#pragma unroll
      for (int kk = 0; kk < 4; ++kk) {
        s16x8 pbf = *(const s16x8*)((char*)plds[wv] +
                      ((qcol * 128 + (16 * kk + 8 * h) * 2) ^ swzK(qcol)));
#pragma unroll
        for (int mt = 0; mt < 2; ++mt) {
          int dr = 32 * mt + qcol;
          s16x8 vbr = *(const s16x8*)((char*)vlds[wv] +
                        ((dr * 128 + (16 * kk + 8 * h) * 2) ^ swzV(dr)));
          o[mt] = __builtin_amdgcn_mfma_f32_32x32x16_bf16(vbr, pbf, o[mt], 0, 0, 0);
        }
      }
      __builtin_amdgcn_s_setprio(0);
    }
  }

  // ---- 4-way flash merge (wave 0 combines), ctx -> LDS bf16 [q][d] ----
  __syncthreads();
  float* obuf  = (float*)klds;          // 3 waves x 2048 f32 = 24 KB (dead now)
  float* mstat = (float*)vlds;          // 3 x 128 f32 (dead now)
  unsigned short* clds = &plds[0][0];   // ctx tile 32x64 bf16 = 4 KB (dead now)
  if (wv != 0) {
#pragma unroll
    for (int mt = 0; mt < 2; ++mt)
#pragma unroll
      for (int rg = 0; rg < 16; ++rg)
        obuf[(wv - 1) * 2048 + (mt * 16 + rg) * 64 + lane] = o[mt][rg];
    mstat[(wv - 1) * 128 + lane] = m_run;
    mstat[(wv - 1) * 128 + 64 + lane] = l_run;
  }
  __syncthreads();
  if (wv == 0) {
    float mB[3], lB[3];
    float mS = m_run;
#pragma unroll
    for (int i = 0; i < 3; ++i) {
      mB[i] = mstat[i * 128 + lane];
      lB[i] = mstat[i * 128 + 64 + lane];
      mS = fmaxf(mS, mB[i]);
    }
    float f0 = exp2f(m_run - mS);
    float fi[3];
    float l_tot = l_run * f0;
#pragma unroll
    for (int i = 0; i < 3; ++i) { fi[i] = exp2f(mB[i] - mS); l_tot += lB[i] * fi[i]; }
    float inv = 1.0f / l_tot;
#pragma unroll
    for (int mt = 0; mt < 2; ++mt) {
#pragma unroll
      for (int rgq = 0; rgq < 4; ++rgq) {
        s16x4 pb;
#pragma unroll
        for (int e = 0; e < 4; ++e) {
          int rg = 4 * rgq + e;
          float val = o[mt][rg] * f0;
#pragma unroll
          for (int i = 0; i < 3; ++i)
            val += obuf[i * 2048 + (mt * 16 + rg) * 64 + lane] * fi[i];
          pb[e] = (short)f2bf(val * inv);
        }
        int d0 = 32 * mt + 8 * rgq + 4 * h;
        int byte = qcol * 128 + d0 * 2;
        *(s16x4*)((char*)clds + (byte ^ swzK(qcol))) = pb;
      }
    }
  }
  __syncthreads();

  // ---- fused output projection: out[q0..q0+32) x 1024 = ctx(32x64) . Wo^T ----
  s16x8 afr[2][2];
#pragma unroll
  for (int mt = 0; mt < 2; ++mt)
#pragma unroll
    for (int kk = 0; kk < 2; ++kk) {
      int ra = 16 * mt + c;
      afr[mt][kk] = *(const s16x8*)((char*)clds +
                      ((ra * 128 + (32 * kk + 8 * g) * 2) ^ swzK(ra)));
    }
  const int n0w = wv * 256;
  const size_t orow0 = (size_t)(b * TT + q0);
#pragma unroll 4
  for (int nt = 0; nt < 16; ++nt) {
    int col = n0w + 16 * nt + c;
    s16x8 bfr[2];
#pragma unroll
    for (int kk = 0; kk < 2; ++kk)
      bfr[kk] = *(const s16x8*)(Wo_b + (size_t)col * DD + 32 * kk + 8 * g);
    f32x4 acc4[2];
#pragma unroll
    for (int mt = 0; mt < 2; ++mt)
#pragma unroll
      for (int e = 0; e < 4; ++e) acc4[mt][e] = 0.0f;
#pragma unroll
    for (int kk = 0; kk < 2; ++kk)
#pragma unroll
      for (int mt = 0; mt < 2; ++mt)
        acc4[mt] = __builtin_amdgcn_mfma_f32_16x16x32_bf16(afr[mt][kk], bfr[kk],
                                                           acc4[mt], 0, 0, 0);
    float bias = bo[col];
#pragma unroll
    for (int mt = 0; mt < 2; ++mt)
#pragma unroll
      for (int i = 0; i < 4; ++i) {
        size_t row = orow0 + 16 * mt + 4 * g + i;
        out[row * HH + col] = acc4[mt][i] + bias;
      }
  }
}

// ---------------------------------------------------------------------------
extern "C" void kernel_launch(void* const* d_in, const int* in_sizes, int n_in,
                              void* d_out, int out_size, void* d_ws, size_t ws_size,
                              hipStream_t stream)
{
  const float* y  = (const float*)d_in[0];
  const float* Wq = (const float*)d_in[1];
  const float* bq = (const float*)d_in[2];
  const float* Wk = (const float*)d_in[3];
  const float* bk = (const float*)d_in[4];
  const float* Wv = (const float*)d_in[5];
  const float* bv = (const float*)d_in[6];
  const float* Wo = (const float*)d_in[7];
  const float* bo = (const float*)d_in[8];
  float* out = (float*)d_out;
  char* ws = (char*)d_ws;
  // workspace layout (bytes) — total 6,815,744 (6.5 MiB)
  unsigned short* Wall = (unsigned short*)(ws);                        // 384 KiB
  unsigned short* Wo_b = (unsigned short*)(ws + 393216);               // 128 KiB
  unsigned short* q_ws = (unsigned short*)(ws + 524288);               // 2 MiB
  unsigned short* k_ws = (unsigned short*)(ws + 524288 + 2097152);     // 2 MiB
  unsigned short* v_ws = (unsigned short*)(ws + 524288 + 2 * 2097152); // 2 MiB

  prep_kernel<<<dim3(256), dim3(256), 0, stream>>>(Wq, Wk, Wv, Wo, Wall, Wo_b);
  qkv_kernel<<<dim3(256), dim3(256), 0, stream>>>(y, Wall, bq, bk, bv, q_ws, k_ws, v_ws);
  attn_kernel<<<dim3(512), dim3(256), 0, stream>>>(q_ws, k_ws, v_ws, Wo_b, bo, out);
}

// Round 5
// 77.254 us; speedup vs baseline: 1.4019x; 1.2731x over previous
//
#include <hip/hip_runtime.h>

// ---------------------------------------------------------------------------
// Causal self-attention, B=4 T=4096 H=1024 D=64, fp32 in/out, bf16 MFMA inside.
// prep (weights->bf16) -> qkv GEMM (V stored TRANSPOSED) -> fused barrier-free
// flash attention + out-proj (K/Q/V^T fragments loaded directly from L2;
// P^T built in-register via f2bf packing + shfl_xor(32) half-exchange).
// ws usage: 6.5 MiB (Wall 384K | Wo_b 128K | q 2M | k 2M | vT 2M).
// ---------------------------------------------------------------------------

typedef __attribute__((ext_vector_type(4)))  float f32x4;
typedef __attribute__((ext_vector_type(16))) float f32x16;
typedef __attribute__((ext_vector_type(8)))  short s16x8;
typedef __attribute__((ext_vector_type(4)))  short s16x4;

#define DEV static __device__ __forceinline__

static constexpr int TT = 4096;        // sequence length
static constexpr int HH = 1024;        // hidden
static constexpr int DD = 64;          // head dim
static constexpr float MNEG = -3.0e38f; // finite -inf substitute (NaN-proof)

DEV unsigned short f2bf(float f) {     // round-to-nearest-even fp32->bf16
  union { float f; unsigned int u; } v; v.f = f;
  unsigned int r = v.u + 0x7FFFu + ((v.u >> 16) & 1u);
  return (unsigned short)(r >> 16);
}

DEV unsigned int pk2(float lo, float hi) {   // two bf16 in one u32
  return (unsigned int)f2bf(lo) | ((unsigned int)f2bf(hi) << 16);
}

DEV s16x8 mk8(unsigned int w0, unsigned int w1, unsigned int w2, unsigned int w3) {
  union { unsigned int u[4]; s16x8 v; } c;
  c.u[0] = w0; c.u[1] = w1; c.u[2] = w2; c.u[3] = w3; return c.v;
}

// XOR swizzles for 128B-row LDS tiles (bank-conflict avoidance)
DEV int swzA(int row) { return ((row & 7) << 4); }                     // 16-row tiles
DEV int swzK(int row) { return ((row & 7) << 4) ^ ((row & 8) << 3); }  // 32-row tiles

// ---------------------------------------------------------------------------
// Kernel 0: weights fp32 -> bf16.  Wall rows: [0,64)=Wq [64,128)=Wk [128,192)=Wv
// ---------------------------------------------------------------------------
__global__ void prep_kernel(const float* __restrict__ Wq, const float* __restrict__ Wk,
                            const float* __restrict__ Wv, const float* __restrict__ Wo,
                            unsigned short* __restrict__ Wall,
                            unsigned short* __restrict__ Wo_b)
{
  int i = blockIdx.x * blockDim.x + threadIdx.x;
  int stride = gridDim.x * blockDim.x;
  const int n1 = 64 * HH;
  for (int idx = i; idx < 3 * n1; idx += stride) {
    float v = idx < n1 ? Wq[idx] : (idx < 2 * n1 ? Wk[idx - n1] : Wv[idx - 2 * n1]);
    Wall[idx] = f2bf(v);
  }
  for (int idx = i; idx < HH * DD; idx += stride) Wo_b[idx] = f2bf(Wo[idx]);
}

// ---------------------------------------------------------------------------
// Kernel 1: QKV projection.  q/k[bt][64] bf16 (q pre-scaled log2e/8);
// v stored TRANSPOSED: vT[b][d][t].  256 blocks x 256 thr, K=1024 in 16 steps.
// ---------------------------------------------------------------------------
__global__ __launch_bounds__(256) void qkv_kernel(
    const float* __restrict__ y, const unsigned short* __restrict__ Wall,
    const float* __restrict__ bq, const float* __restrict__ bk,
    const float* __restrict__ bv,
    unsigned short* __restrict__ q_ws, unsigned short* __restrict__ k_ws,
    unsigned short* __restrict__ vT_ws)
{
  __shared__ unsigned short ylds[2][64 * 64];
  __shared__ unsigned short wlds[2][192 * 64];
  const int t = threadIdx.x;
  const int w = t >> 6, lane = t & 63, g = lane >> 4, c = lane & 15;
  const int row0 = blockIdx.x * 64;
  const int yrow = t >> 2, ycol0 = (t & 3) * 16;

  f32x4 acc[12];
#pragma unroll
  for (int i = 0; i < 12; ++i)
#pragma unroll
    for (int e = 0; e < 4; ++e) acc[i][e] = 0.0f;

  f32x4 yr[4];
  s16x8 wr[6];

  auto load_tiles = [&](int kb) {
    const float* src = y + (size_t)(row0 + yrow) * HH + kb * 64 + ycol0;
    yr[0] = *(const f32x4*)(src);
    yr[1] = *(const f32x4*)(src + 4);
    yr[2] = *(const f32x4*)(src + 8);
    yr[3] = *(const f32x4*)(src + 12);
#pragma unroll
    for (int ii = 0; ii < 6; ++ii) {
      int ch = t + ii * 256;
      int rw = ch >> 3, c0 = (ch & 7) * 8;
      wr[ii] = *(const s16x8*)(Wall + (size_t)rw * HH + kb * 64 + c0);
    }
  };
  auto write_tiles = [&](int buf) {
    s16x8 h0, h1;
#pragma unroll
    for (int e = 0; e < 4; ++e) {
      h0[e]     = (short)f2bf(yr[0][e]);
      h0[e + 4] = (short)f2bf(yr[1][e]);
      h1[e]     = (short)f2bf(yr[2][e]);
      h1[e + 4] = (short)f2bf(yr[3][e]);
    }
    int byte0 = yrow * 128 + ycol0 * 2;
    *(s16x8*)((char*)ylds[buf] + (byte0 ^ swzA(yrow)))        = h0;
    *(s16x8*)((char*)ylds[buf] + ((byte0 + 16) ^ swzA(yrow))) = h1;
#pragma unroll
    for (int ii = 0; ii < 6; ++ii) {
      int ch = t + ii * 256;
      int rw = ch >> 3, c0 = (ch & 7) * 8;
      int byte = rw * 128 + c0 * 2;
      *(s16x8*)((char*)wlds[buf] + (byte ^ swzA(rw))) = wr[ii];
    }
  };

  load_tiles(0);
  write_tiles(0);
  __syncthreads();
  for (int kb = 0; kb < 16; ++kb) {
    int buf = kb & 1;
    if (kb < 15) load_tiles(kb + 1);
#pragma unroll
    for (int kk = 0; kk < 2; ++kk) {
      int r = 16 * w + c;
      s16x8 a = *(const s16x8*)((char*)ylds[buf] +
                  ((r * 128 + (kk * 32 + 8 * g) * 2) ^ swzA(r)));
#pragma unroll
      for (int nt = 0; nt < 12; ++nt) {
        int rb = 16 * nt + c;
        s16x8 b = *(const s16x8*)((char*)wlds[buf] +
                    ((rb * 128 + (kk * 32 + 8 * g) * 2) ^ swzA(rb)));
        acc[nt] = __builtin_amdgcn_mfma_f32_16x16x32_bf16(a, b, acc[nt], 0, 0, 0);
      }
    }
    __syncthreads();
    if (kb < 15) { write_tiles((kb + 1) & 1); __syncthreads(); }
  }

  const float qsc = 1.4426950408889634f / 8.0f;   // log2e / sqrt(Dk)
#pragma unroll
  for (int nt = 0; nt < 12; ++nt) {
    int col = 16 * nt + c;
    int sec = nt >> 2;
    int dcol = col & 63;
    float bias = sec == 0 ? bq[dcol] : (sec == 1 ? bk[dcol] : bv[dcol]);
    if (sec == 2) {
      // vT[b][dcol][t], 4 consecutive t per lane -> one 8B store
      s16x4 pv;
#pragma unroll
      for (int i = 0; i < 4; ++i) pv[i] = (short)f2bf(acc[nt][i] + bias);
      int bb = row0 >> 12;
      int t0 = (row0 & 4095) + 16 * w + 4 * g;
      *(s16x4*)(vT_ws + (size_t)bb * (DD * TT) + (size_t)dcol * TT + t0) = pv;
    } else {
      unsigned short* dst = sec == 0 ? q_ws : k_ws;
#pragma unroll
      for (int i = 0; i < 4; ++i) {
        int row = row0 + 16 * w + 4 * g + i;
        float val = acc[nt][i] + bias;
        if (sec == 0) val *= qsc;
        dst[(size_t)row * DD + dcol] = f2bf(val);
      }
    }
  }
}

// ---------------------------------------------------------------------------
// Kernel 2: fused barrier-free flash attention + output projection.
// Grid 512 = 4 b x 128 q-tiles (32 rows); complementary pairing j32(s) so that
// CU pair (block c, c+256) sums to a constant 65 tile-computes.
// 4 waves = 4-way KV parity, fully independent until the final merge.
// S^T = K.Q^T (32x32x16): q = lane&31 -> per-lane softmax over the lane's 32
// scores + one shfl_xor(32) to combine h-halves (each lane holds only the
// kv offsets at 4h within the 64-kv tile -- the combine is REQUIRED).
// P^T packed in-register (f2bf); h-half exchange via shfl_xor(32)+select.
// O^T += V^T.P^T with V^T frags straight from global (vT layout).
// ---------------------------------------------------------------------------
__global__ __launch_bounds__(256, 2) void attn_kernel(
    const unsigned short* __restrict__ q_ws, const unsigned short* __restrict__ k_ws,
    const unsigned short* __restrict__ vT_ws, const unsigned short* __restrict__ Wo_b,
    const float* __restrict__ bo, float* __restrict__ out)
{
  __shared__ float obuf[3 * 2048];          // waves 1-3 O^T          (24 KB)
  __shared__ float mstat[3 * 128];          // waves 1-3 m,l          (1.5 KB)
  __shared__ unsigned short clds[32 * 64];  // merged ctx bf16 [q][d] (4 KB)
  const int t = threadIdx.x, wv = t >> 6, lane = t & 63;
  const int qcol = lane & 31, h = lane >> 5;
  const int b = blockIdx.x & 3;
  const int jslot = blockIdx.x >> 2;
  const int j32 = (jslot < 64) ? (2 * jslot) : (127 - 2 * (jslot - 64));
  const int q0 = j32 * 32;
  const int L = j32 >> 1;                   // last KV tile (diagonal)
  const size_t base  = (size_t)b * TT * DD; // q,k: [t][d]
  const size_t vbase = (size_t)b * DD * TT; // vT:  [d][t]
  const int g = lane >> 4, c = lane & 15;   // proj phase

  // Q B-frags: lane holds Q[q0+qcol][16*kk+8*h + j]
  s16x8 qf[4];
  {
    const unsigned short* qp = q_ws + base + (size_t)(q0 + qcol) * DD + 8 * h;
#pragma unroll
    for (int kk = 0; kk < 4; ++kk) qf[kk] = *(const s16x8*)(qp + 16 * kk);
  }
  f32x16 o[2];
#pragma unroll
  for (int mt = 0; mt < 2; ++mt)
#pragma unroll
    for (int rg = 0; rg < 16; ++rg) o[mt][rg] = 0.0f;
  float m_run = MNEG, l_run = 0.0f;

  for (int kt = wv; kt <= L; kt += 4) {
    const int kv0 = kt * 64;
    // ---- K A-frags from global: K[kv0+32mt+(lane&31)][16kk+8h ..+7] ----
    s16x8 kf[2][4];
#pragma unroll
    for (int mt = 0; mt < 2; ++mt)
#pragma unroll
      for (int kk = 0; kk < 4; ++kk)
        kf[mt][kk] = *(const s16x8*)(k_ws + base +
                       (size_t)(kv0 + 32 * mt + qcol) * DD + 16 * kk + 8 * h);
    // ---- S^T = K . Q^T ----
    f32x16 s[2];
#pragma unroll
    for (int mt = 0; mt < 2; ++mt)
#pragma unroll
      for (int rg = 0; rg < 16; ++rg) s[mt][rg] = 0.0f;
    __builtin_amdgcn_s_setprio(1);
#pragma unroll
    for (int kk = 0; kk < 4; ++kk)
#pragma unroll
      for (int mt = 0; mt < 2; ++mt)
        s[mt] = __builtin_amdgcn_mfma_f32_32x32x16_bf16(kf[mt][kk], qf[kk], s[mt], 0, 0, 0);
    __builtin_amdgcn_s_setprio(0);
    // ---- V^T A-frags (issued early; consumed after softmax) ----
    s16x8 vf[2][4];
#pragma unroll
    for (int mt = 0; mt < 2; ++mt)
#pragma unroll
      for (int ks = 0; ks < 4; ++ks)
        vf[mt][ks] = *(const s16x8*)(vT_ws + vbase +
                       (size_t)(32 * mt + qcol) * TT + kv0 + 16 * ks + 8 * h);
    // ---- causal mask (diagonal tile only) ----
    if (kt == L) {
      int qq = q0 + qcol;
#pragma unroll
      for (int mt = 0; mt < 2; ++mt)
#pragma unroll
        for (int rg = 0; rg < 16; ++rg) {
          int kvabs = kv0 + 32 * mt + (rg & 3) + 8 * (rg >> 2) + 4 * h;
          if (kvabs > qq) s[mt][rg] = MNEG;
        }
    }
    // ---- online softmax (log2 domain): per-lane tree + cross-half shfl ----
    float mx[16];
#pragma unroll
    for (int e = 0; e < 16; ++e) mx[e] = fmaxf(s[0][e], s[1][e]);
#pragma unroll
    for (int st = 8; st >= 1; st >>= 1)
#pragma unroll
      for (int e = 0; e < 8; ++e) if (e < st) mx[e] = fmaxf(mx[e], mx[e + st]);
    float pm = fmaxf(mx[0], __shfl_xor(mx[0], 32));   // REQUIRED: other h-half
    float m_new = fmaxf(m_run, pm);
    float alpha = exp2f(m_run - m_new);
#pragma unroll
    for (int mt = 0; mt < 2; ++mt)
#pragma unroll
      for (int rg = 0; rg < 16; ++rg) s[mt][rg] = exp2f(s[mt][rg] - m_new);
    float sm[16];
#pragma unroll
    for (int e = 0; e < 16; ++e) sm[e] = s[0][e] + s[1][e];
#pragma unroll
    for (int st = 8; st >= 1; st >>= 1)
#pragma unroll
      for (int e = 0; e < 8; ++e) if (e < st) sm[e] += sm[e + st];
    float rowsum = sm[0] + __shfl_xor(sm[0], 32);     // REQUIRED: other h-half
    l_run = l_run * alpha + rowsum;
    m_run = m_new;
#pragma unroll
    for (int mt = 0; mt < 2; ++mt)
#pragma unroll
      for (int rg = 0; rg < 16; ++rg) o[mt][rg] *= alpha;
    // ---- pack P^T B-frags in-register ----
    // lane holds P[q][kv=32mt+(rg&3)+8(rg>>2)+4h]; B-frag pf[ks] word w must
    // be P[q][16ks+8h+2w..+1].  Exchange: word X.h1 <-> partner Y.h0 via one
    // shfl_xor(32) + selects (t = shfl(h?X:Y); w_lo = h?t:X; w_hi = h?Y:t).
    s16x8 pf[4];
#pragma unroll
    for (int mt = 0; mt < 2; ++mt) {
      unsigned int a0 = pk2(s[mt][0],  s[mt][1]);   // kv 4h+0,1
      unsigned int a1 = pk2(s[mt][2],  s[mt][3]);   // kv 4h+2,3
      unsigned int b0 = pk2(s[mt][4],  s[mt][5]);   // kv 8+4h+0,1
      unsigned int b1 = pk2(s[mt][6],  s[mt][7]);   // kv 8+4h+2,3
      unsigned int c0 = pk2(s[mt][8],  s[mt][9]);   // kv 16+4h+0,1
      unsigned int c1 = pk2(s[mt][10], s[mt][11]);  // kv 16+4h+2,3
      unsigned int d0 = pk2(s[mt][12], s[mt][13]);  // kv 24+4h+0,1
      unsigned int d1 = pk2(s[mt][14], s[mt][15]);  // kv 24+4h+2,3
      unsigned int t0 = __shfl_xor(h ? a0 : b0, 32);
      unsigned int t1 = __shfl_xor(h ? a1 : b1, 32);
      unsigned int t2 = __shfl_xor(h ? c0 : d0, 32);
      unsigned int t3 = __shfl_xor(h ? c1 : d1, 32);
      pf[2 * mt]     = mk8(h ? t0 : a0, h ? t1 : a1, h ? b0 : t0, h ? b1 : t1);
      pf[2 * mt + 1] = mk8(h ? t2 : c0, h ? t3 : c1, h ? d0 : t2, h ? d1 : t3);
    }
    // ---- O^T += V^T . P^T ----
    __builtin_amdgcn_s_setprio(1);
#pragma unroll
    for (int ks = 0; ks < 4; ++ks)
#pragma unroll
      for (int mt = 0; mt < 2; ++mt)
        o[mt] = __builtin_amdgcn_mfma_f32_32x32x16_bf16(vf[mt][ks], pf[ks], o[mt], 0, 0, 0);
    __builtin_amdgcn_s_setprio(0);
  }

  // ---- 4-way flash merge (wave 0 combines), ctx -> LDS bf16 [q][d] ----
  if (wv != 0) {
#pragma unroll
    for (int mt = 0; mt < 2; ++mt)
#pragma unroll
      for (int rg = 0; rg < 16; ++rg)
        obuf[(wv - 1) * 2048 + (mt * 16 + rg) * 64 + lane] = o[mt][rg];
    mstat[(wv - 1) * 128 + lane] = m_run;
    mstat[(wv - 1) * 128 + 64 + lane] = l_run;
  }
  __syncthreads();
  if (wv == 0) {
    float mB[3], lB[3];
    float mS = m_run;
#pragma unroll
    for (int i = 0; i < 3; ++i) {
      mB[i] = mstat[i * 128 + lane];
      lB[i] = mstat[i * 128 + 64 + lane];
      mS = fmaxf(mS, mB[i]);
    }
    float f0 = exp2f(m_run - mS);
    float fi[3];
    float l_tot = l_run * f0;
#pragma unroll
    for (int i = 0; i < 3; ++i) { fi[i] = exp2f(mB[i] - mS); l_tot += lB[i] * fi[i]; }
    float inv = 1.0f / l_tot;
#pragma unroll
    for (int mt = 0; mt < 2; ++mt) {
#pragma unroll
      for (int rgq = 0; rgq < 4; ++rgq) {
        s16x4 pb;
#pragma unroll
        for (int e = 0; e < 4; ++e) {
          int rg = 4 * rgq + e;
          float val = o[mt][rg] * f0;
#pragma unroll
          for (int i = 0; i < 3; ++i)
            val += obuf[i * 2048 + (mt * 16 + rg) * 64 + lane] * fi[i];
          pb[e] = (short)f2bf(val * inv);
        }
        int d0 = 32 * mt + 8 * rgq + 4 * h;
        int byte = qcol * 128 + d0 * 2;
        *(s16x4*)((char*)clds + (byte ^ swzK(qcol))) = pb;
      }
    }
  }
  __syncthreads();

  // ---- fused output projection: out[q0..q0+32) x 1024 = ctx(32x64) . Wo^T ----
  s16x8 afr[2][2];
#pragma unroll
  for (int mt = 0; mt < 2; ++mt)
#pragma unroll
    for (int kk = 0; kk < 2; ++kk) {
      int ra = 16 * mt + c;
      afr[mt][kk] = *(const s16x8*)((char*)clds +
                      ((ra * 128 + (32 * kk + 8 * g) * 2) ^ swzK(ra)));
    }
  const int n0w = wv * 256;
  const size_t orow0 = (size_t)(b * TT + q0);
#pragma unroll 4
  for (int nt = 0; nt < 16; ++nt) {
    int col = n0w + 16 * nt + c;
    s16x8 bfr[2];
#pragma unroll
    for (int kk = 0; kk < 2; ++kk)
      bfr[kk] = *(const s16x8*)(Wo_b + (size_t)col * DD + 32 * kk + 8 * g);
    f32x4 acc4[2];
#pragma unroll
    for (int mt = 0; mt < 2; ++mt)
#pragma unroll
      for (int e = 0; e < 4; ++e) acc4[mt][e] = 0.0f;
#pragma unroll
    for (int kk = 0; kk < 2; ++kk)
#pragma unroll
      for (int mt = 0; mt < 2; ++mt)
        acc4[mt] = __builtin_amdgcn_mfma_f32_16x16x32_bf16(afr[mt][kk], bfr[kk],
                                                           acc4[mt], 0, 0, 0);
    float bias = bo[col];
#pragma unroll
    for (int mt = 0; mt < 2; ++mt)
#pragma unroll
      for (int i = 0; i < 4; ++i) {
        size_t row = orow0 + 16 * mt + 4 * g + i;
        out[row * HH + col] = acc4[mt][i] + bias;
      }
  }
}

// ---------------------------------------------------------------------------
extern "C" void kernel_launch(void* const* d_in, const int* in_sizes, int n_in,
                              void* d_out, int out_size, void* d_ws, size_t ws_size,
                              hipStream_t stream)
{
  const float* y  = (const float*)d_in[0];
  const float* Wq = (const float*)d_in[1];
  const float* bq = (const float*)d_in[2];
  const float* Wk = (const float*)d_in[3];
  const float* bk = (const float*)d_in[4];
  const float* Wv = (const float*)d_in[5];
  const float* bv = (const float*)d_in[6];
  const float* Wo = (const float*)d_in[7];
  const float* bo = (const float*)d_in[8];
  float* out = (float*)d_out;
  char* ws = (char*)d_ws;
  // workspace layout (bytes) — total 6,815,744 (6.5 MiB)
  unsigned short* Wall  = (unsigned short*)(ws);                        // 384 KiB
  unsigned short* Wo_b  = (unsigned short*)(ws + 393216);               // 128 KiB
  unsigned short* q_ws  = (unsigned short*)(ws + 524288);               // 2 MiB
  unsigned short* k_ws  = (unsigned short*)(ws + 524288 + 2097152);     // 2 MiB
  unsigned short* vT_ws = (unsigned short*)(ws + 524288 + 2 * 2097152); // 2 MiB

  prep_kernel<<<dim3(256), dim3(256), 0, stream>>>(Wq, Wk, Wv, Wo, Wall, Wo_b);
  qkv_kernel<<<dim3(256), dim3(256), 0, stream>>>(y, Wall, bq, bk, bv, q_ws, k_ws, vT_ws);
  attn_kernel<<<dim3(512), dim3(256), 0, stream>>>(q_ws, k_ws, vT_ws, Wo_b, bo, out);
}

// Round 6
// 64.751 us; speedup vs baseline: 1.6726x; 1.1931x over previous
//
#include <hip/hip_runtime.h>

// ---------------------------------------------------------------------------
// Causal self-attention, B=4 T=4096 H=1024 D=64, fp32 in/out, bf16 MFMA inside.
// prep (weights->bf16) -> qkv GEMM -> fused barrier-free flash attn + out-proj.
// KEY: q/k/vT/Wo_b are stored in MFMA-FRAGMENT-NATIVE layouts so every
// fragment load in attn is one contiguous 1KB wave-load (no 128B-stride
// gathers through L1/TA).  P^T built in-register (f2bf + shfl_xor(32)).
// ws usage: 6.5 MiB (Wall 384K | Wo_b 128K | q 2M | k 2M | vT 2M).
//
// Layouts (elements, per batch b):
//   q/k (t, d):  b*T*D + (t>>5)*2048 + (d>>4)*512 + (t&31)*16 + (d&15)
//   vT  (d, t):  b*D*T + (t>>6)*4096 + (d>>5)*2048 + ((t>>4)&3)*512
//                + (d&31)*16 + (t&15)
//   Wo_b(hcol,d): (hcol>>4)*1024 + (d>>5)*512 + (hcol&15)*32 + ((d>>3)&3)*8 + (d&7)
// ---------------------------------------------------------------------------

typedef __attribute__((ext_vector_type(4)))  float f32x4;
typedef __attribute__((ext_vector_type(16))) float f32x16;
typedef __attribute__((ext_vector_type(8)))  short s16x8;
typedef __attribute__((ext_vector_type(4)))  short s16x4;

#define DEV static __device__ __forceinline__

static constexpr int TT = 4096;        // sequence length
static constexpr int HH = 1024;        // hidden
static constexpr int DD = 64;          // head dim
static constexpr float MNEG = -3.0e38f; // finite -inf substitute (NaN-proof)

DEV unsigned short f2bf(float f) {     // round-to-nearest-even fp32->bf16
  union { float f; unsigned int u; } v; v.f = f;
  unsigned int r = v.u + 0x7FFFu + ((v.u >> 16) & 1u);
  return (unsigned short)(r >> 16);
}

DEV unsigned int pk2(float lo, float hi) {   // two bf16 in one u32
  return (unsigned int)f2bf(lo) | ((unsigned int)f2bf(hi) << 16);
}

DEV s16x8 mk8(unsigned int w0, unsigned int w1, unsigned int w2, unsigned int w3) {
  union { unsigned int u[4]; s16x8 v; } c;
  c.u[0] = w0; c.u[1] = w1; c.u[2] = w2; c.u[3] = w3; return c.v;
}

// XOR swizzles for 128B-row LDS tiles (bank-conflict avoidance)
DEV int swzA(int row) { return ((row & 7) << 4); }                     // 16-row tiles
DEV int swzK(int row) { return ((row & 7) << 4) ^ ((row & 8) << 3); }  // 32-row tiles

// ---------------------------------------------------------------------------
// Kernel 0: weights fp32 -> bf16.  Wall rows: [0,64)=Wq [64,128)=Wk [128,192)=Wv
// Wo_b written in proj-fragment layout.
// ---------------------------------------------------------------------------
__global__ void prep_kernel(const float* __restrict__ Wq, const float* __restrict__ Wk,
                            const float* __restrict__ Wv, const float* __restrict__ Wo,
                            unsigned short* __restrict__ Wall,
                            unsigned short* __restrict__ Wo_b)
{
  int i = blockIdx.x * blockDim.x + threadIdx.x;
  int stride = gridDim.x * blockDim.x;
  const int n1 = 64 * HH;
  for (int idx = i; idx < 3 * n1; idx += stride) {
    float v = idx < n1 ? Wq[idx] : (idx < 2 * n1 ? Wk[idx - n1] : Wv[idx - 2 * n1]);
    Wall[idx] = f2bf(v);
  }
  for (int idx = i; idx < HH * DD; idx += stride) {
    int hcol = idx >> 6, d = idx & 63;
    size_t off = (size_t)(hcol >> 4) * 1024 + (d >> 5) * 512 + (hcol & 15) * 32
               + ((d >> 3) & 3) * 8 + (d & 7);
    Wo_b[off] = f2bf(Wo[idx]);
  }
}

// ---------------------------------------------------------------------------
// Kernel 1: QKV projection.  Outputs in fragment-native layouts (see header);
// q pre-scaled by log2e/8.  256 blocks x 256 thr, K=1024 in 16 steps of 64.
// ---------------------------------------------------------------------------
__global__ __launch_bounds__(256) void qkv_kernel(
    const float* __restrict__ y, const unsigned short* __restrict__ Wall,
    const float* __restrict__ bq, const float* __restrict__ bk,
    const float* __restrict__ bv,
    unsigned short* __restrict__ q_ws, unsigned short* __restrict__ k_ws,
    unsigned short* __restrict__ vT_ws)
{
  __shared__ unsigned short ylds[2][64 * 64];
  __shared__ unsigned short wlds[2][192 * 64];
  const int t = threadIdx.x;
  const int w = t >> 6, lane = t & 63, g = lane >> 4, c = lane & 15;
  const int row0 = blockIdx.x * 64;
  const int yrow = t >> 2, ycol0 = (t & 3) * 16;

  f32x4 acc[12];
#pragma unroll
  for (int i = 0; i < 12; ++i)
#pragma unroll
    for (int e = 0; e < 4; ++e) acc[i][e] = 0.0f;

  f32x4 yr[4];
  s16x8 wr[6];

  auto load_tiles = [&](int kb) {
    const float* src = y + (size_t)(row0 + yrow) * HH + kb * 64 + ycol0;
    yr[0] = *(const f32x4*)(src);
    yr[1] = *(const f32x4*)(src + 4);
    yr[2] = *(const f32x4*)(src + 8);
    yr[3] = *(const f32x4*)(src + 12);
#pragma unroll
    for (int ii = 0; ii < 6; ++ii) {
      int ch = t + ii * 256;
      int rw = ch >> 3, c0 = (ch & 7) * 8;
      wr[ii] = *(const s16x8*)(Wall + (size_t)rw * HH + kb * 64 + c0);
    }
  };
  auto write_tiles = [&](int buf) {
    s16x8 h0, h1;
#pragma unroll
    for (int e = 0; e < 4; ++e) {
      h0[e]     = (short)f2bf(yr[0][e]);
      h0[e + 4] = (short)f2bf(yr[1][e]);
      h1[e]     = (short)f2bf(yr[2][e]);
      h1[e + 4] = (short)f2bf(yr[3][e]);
    }
    int byte0 = yrow * 128 + ycol0 * 2;
    *(s16x8*)((char*)ylds[buf] + (byte0 ^ swzA(yrow)))        = h0;
    *(s16x8*)((char*)ylds[buf] + ((byte0 + 16) ^ swzA(yrow))) = h1;
#pragma unroll
    for (int ii = 0; ii < 6; ++ii) {
      int ch = t + ii * 256;
      int rw = ch >> 3, c0 = (ch & 7) * 8;
      int byte = rw * 128 + c0 * 2;
      *(s16x8*)((char*)wlds[buf] + (byte ^ swzA(rw))) = wr[ii];
    }
  };

  load_tiles(0);
  write_tiles(0);
  __syncthreads();
  for (int kb = 0; kb < 16; ++kb) {
    int buf = kb & 1;
    if (kb < 15) load_tiles(kb + 1);
#pragma unroll
    for (int kk = 0; kk < 2; ++kk) {
      int r = 16 * w + c;
      s16x8 a = *(const s16x8*)((char*)ylds[buf] +
                  ((r * 128 + (kk * 32 + 8 * g) * 2) ^ swzA(r)));
#pragma unroll
      for (int nt = 0; nt < 12; ++nt) {
        int rb = 16 * nt + c;
        s16x8 b = *(const s16x8*)((char*)wlds[buf] +
                    ((rb * 128 + (kk * 32 + 8 * g) * 2) ^ swzA(rb)));
        acc[nt] = __builtin_amdgcn_mfma_f32_16x16x32_bf16(a, b, acc[nt], 0, 0, 0);
      }
    }
    __syncthreads();
    if (kb < 15) { write_tiles((kb + 1) & 1); __syncthreads(); }
  }

  // epilogue: bias (+ q scale), store into fragment-native layouts
  const float qsc = 1.4426950408889634f / 8.0f;   // log2e / sqrt(Dk)
  const int bb = row0 >> 12;
  const int tb = row0 & 4095;                      // 64-aligned
#pragma unroll
  for (int nt = 0; nt < 12; ++nt) {
    int sec = nt >> 2;
    int dcol = (nt & 3) * 16 + c;
    float bias = sec == 0 ? bq[dcol] : (sec == 1 ? bk[dcol] : bv[dcol]);
    if (sec == 2) {
      // vT frag layout: 4 consecutive t per lane -> one 8B store
      s16x4 pv;
#pragma unroll
      for (int i = 0; i < 4; ++i) pv[i] = (short)f2bf(acc[nt][i] + bias);
      int t0 = tb + 16 * w + 4 * g;
      size_t off = (size_t)bb * (DD * TT) + (size_t)(t0 >> 6) * 4096
                 + (dcol >> 5) * 2048 + w * 512 + (dcol & 31) * 16 + (t0 & 15);
      *(s16x4*)(vT_ws + off) = pv;
    } else {
      unsigned short* dst = sec == 0 ? q_ws : k_ws;
      int kk = nt & 3;        // dcol>>4 (c<16)
#pragma unroll
      for (int i = 0; i < 4; ++i) {
        int t_in = tb + 16 * w + 4 * g + i;
        float val = acc[nt][i] + bias;
        if (sec == 0) val *= qsc;
        size_t off = (size_t)bb * (TT * DD) + (size_t)(t_in >> 5) * 2048
                   + kk * 512 + (t_in & 31) * 16 + c;
        dst[off] = f2bf(val);
      }
    }
  }
}

// ---------------------------------------------------------------------------
// Kernel 2: fused barrier-free flash attention + output projection.
// Grid 512 = 4 b x 128 q-tiles (32 rows); complementary pairing j32(s) so that
// CU pair (block c, c+256) sums to a constant 65 tile-computes.
// 4 waves = 4-way KV parity, fully independent until the final merge.
// All fragment loads are contiguous 1KB wave-loads (fragment-native layouts).
// S^T = K.Q^T (32x32x16); per-lane softmax + shfl_xor(32) h-half combine.
// P^T packed in-register; O^T += V^T.P^T; 4-way merge; fused 32x1024 proj.
// ---------------------------------------------------------------------------
__global__ __launch_bounds__(256, 2) void attn_kernel(
    const unsigned short* __restrict__ q_ws, const unsigned short* __restrict__ k_ws,
    const unsigned short* __restrict__ vT_ws, const unsigned short* __restrict__ Wo_b,
    const float* __restrict__ bo, float* __restrict__ out)
{
  __shared__ float obuf[3 * 2048];          // waves 1-3 O^T          (24 KB)
  __shared__ float mstat[3 * 128];          // waves 1-3 m,l          (1.5 KB)
  __shared__ unsigned short clds[32 * 64];  // merged ctx bf16 [q][d] (4 KB)
  const int t = threadIdx.x, wv = t >> 6, lane = t & 63;
  const int qcol = lane & 31, h = lane >> 5;
  const int b = blockIdx.x & 3;
  const int jslot = blockIdx.x >> 2;
  const int j32 = (jslot < 64) ? (2 * jslot) : (127 - 2 * (jslot - 64));
  const int q0 = j32 * 32;
  const int L = j32 >> 1;                   // last KV tile (diagonal)
  const size_t base  = (size_t)b * TT * DD; // q,k frag space
  const size_t vbase = (size_t)b * DD * TT; // vT frag space
  const int g = lane >> 4, c = lane & 15;   // proj phase
  const int lchunk = (lane & 31) * 16 + (lane >> 5) * 8;   // frag lane offset

  // Q B-frags (contiguous 1KB per kk)
  s16x8 qf[4];
  {
    const unsigned short* qp = q_ws + base + (size_t)j32 * 2048;
#pragma unroll
    for (int kk = 0; kk < 4; ++kk) qf[kk] = *(const s16x8*)(qp + kk * 512 + lchunk);
  }
  f32x16 o[2];
#pragma unroll
  for (int mt = 0; mt < 2; ++mt)
#pragma unroll
    for (int rg = 0; rg < 16; ++rg) o[mt][rg] = 0.0f;
  float m_run = MNEG, l_run = 0.0f;

  for (int kt = wv; kt <= L; kt += 4) {
    const int kv0 = kt * 64;
    // ---- K A-frags: contiguous 1KB wave-loads ----
    s16x8 kf[2][4];
#pragma unroll
    for (int mt = 0; mt < 2; ++mt)
#pragma unroll
      for (int kk = 0; kk < 4; ++kk)
        kf[mt][kk] = *(const s16x8*)(k_ws + base +
                       (size_t)(2 * kt + mt) * 2048 + kk * 512 + lchunk);
    // ---- S^T = K . Q^T ----
    f32x16 s[2];
#pragma unroll
    for (int mt = 0; mt < 2; ++mt)
#pragma unroll
      for (int rg = 0; rg < 16; ++rg) s[mt][rg] = 0.0f;
    __builtin_amdgcn_s_setprio(1);
#pragma unroll
    for (int kk = 0; kk < 4; ++kk)
#pragma unroll
      for (int mt = 0; mt < 2; ++mt)
        s[mt] = __builtin_amdgcn_mfma_f32_32x32x16_bf16(kf[mt][kk], qf[kk], s[mt], 0, 0, 0);
    __builtin_amdgcn_s_setprio(0);
    // ---- V^T A-frags (issued early; consumed after softmax) ----
    s16x8 vf[2][4];
#pragma unroll
    for (int mt = 0; mt < 2; ++mt)
#pragma unroll
      for (int ks = 0; ks < 4; ++ks)
        vf[mt][ks] = *(const s16x8*)(vT_ws + vbase +
                       (size_t)kt * 4096 + mt * 2048 + ks * 512 + lchunk);
    // ---- causal mask (diagonal tile only) ----
    if (kt == L) {
      int qq = q0 + qcol;
#pragma unroll
      for (int mt = 0; mt < 2; ++mt)
#pragma unroll
        for (int rg = 0; rg < 16; ++rg) {
          int kvabs = kv0 + 32 * mt + (rg & 3) + 8 * (rg >> 2) + 4 * h;
          if (kvabs > qq) s[mt][rg] = MNEG;
        }
    }
    // ---- online softmax (log2 domain): per-lane tree + cross-half shfl ----
    float mx[16];
#pragma unroll
    for (int e = 0; e < 16; ++e) mx[e] = fmaxf(s[0][e], s[1][e]);
#pragma unroll
    for (int st = 8; st >= 1; st >>= 1)
#pragma unroll
      for (int e = 0; e < 8; ++e) if (e < st) mx[e] = fmaxf(mx[e], mx[e + st]);
    float pm = fmaxf(mx[0], __shfl_xor(mx[0], 32));   // REQUIRED: other h-half
    float m_new = fmaxf(m_run, pm);
    float alpha = exp2f(m_run - m_new);
#pragma unroll
    for (int mt = 0; mt < 2; ++mt)
#pragma unroll
      for (int rg = 0; rg < 16; ++rg) s[mt][rg] = exp2f(s[mt][rg] - m_new);
    float sm[16];
#pragma unroll
    for (int e = 0; e < 16; ++e) sm[e] = s[0][e] + s[1][e];
#pragma unroll
    for (int st = 8; st >= 1; st >>= 1)
#pragma unroll
      for (int e = 0; e < 8; ++e) if (e < st) sm[e] += sm[e + st];
    float rowsum = sm[0] + __shfl_xor(sm[0], 32);     // REQUIRED: other h-half
    l_run = l_run * alpha + rowsum;
    m_run = m_new;
#pragma unroll
    for (int mt = 0; mt < 2; ++mt)
#pragma unroll
      for (int rg = 0; rg < 16; ++rg) o[mt][rg] *= alpha;
    // ---- pack P^T B-frags in-register ----
    // lane holds P[q][kv=32mt+(rg&3)+8(rg>>2)+4h]; B-frag pf[ks] word w must
    // be P[q][16ks+8h+2w..+1].  Exchange: word X.h1 <-> partner Y.h0 via one
    // shfl_xor(32) + selects (t = shfl(h?X:Y); w_lo = h?t:X; w_hi = h?Y:t).
    s16x8 pf[4];
#pragma unroll
    for (int mt = 0; mt < 2; ++mt) {
      unsigned int a0 = pk2(s[mt][0],  s[mt][1]);   // kv 4h+0,1
      unsigned int a1 = pk2(s[mt][2],  s[mt][3]);   // kv 4h+2,3
      unsigned int b0 = pk2(s[mt][4],  s[mt][5]);   // kv 8+4h+0,1
      unsigned int b1 = pk2(s[mt][6],  s[mt][7]);   // kv 8+4h+2,3
      unsigned int c0 = pk2(s[mt][8],  s[mt][9]);   // kv 16+4h+0,1
      unsigned int c1 = pk2(s[mt][10], s[mt][11]);  // kv 16+4h+2,3
      unsigned int d0 = pk2(s[mt][12], s[mt][13]);  // kv 24+4h+0,1
      unsigned int d1 = pk2(s[mt][14], s[mt][15]);  // kv 24+4h+2,3
      unsigned int t0 = __shfl_xor(h ? a0 : b0, 32);
      unsigned int t1 = __shfl_xor(h ? a1 : b1, 32);
      unsigned int t2 = __shfl_xor(h ? c0 : d0, 32);
      unsigned int t3 = __shfl_xor(h ? c1 : d1, 32);
      pf[2 * mt]     = mk8(h ? t0 : a0, h ? t1 : a1, h ? b0 : t0, h ? b1 : t1);
      pf[2 * mt + 1] = mk8(h ? t2 : c0, h ? t3 : c1, h ? d0 : t2, h ? d1 : t3);
    }
    // ---- O^T += V^T . P^T ----
    __builtin_amdgcn_s_setprio(1);
#pragma unroll
    for (int ks = 0; ks < 4; ++ks)
#pragma unroll
      for (int mt = 0; mt < 2; ++mt)
        o[mt] = __builtin_amdgcn_mfma_f32_32x32x16_bf16(vf[mt][ks], pf[ks], o[mt], 0, 0, 0);
    __builtin_amdgcn_s_setprio(0);
  }

  // ---- 4-way flash merge (wave 0 combines), ctx -> LDS bf16 [q][d] ----
  if (wv != 0) {
#pragma unroll
    for (int mt = 0; mt < 2; ++mt)
#pragma unroll
      for (int rg = 0; rg < 16; ++rg)
        obuf[(wv - 1) * 2048 + (mt * 16 + rg) * 64 + lane] = o[mt][rg];
    mstat[(wv - 1) * 128 + lane] = m_run;
    mstat[(wv - 1) * 128 + 64 + lane] = l_run;
  }
  __syncthreads();
  if (wv == 0) {
    float mB[3], lB[3];
    float mS = m_run;
#pragma unroll
    for (int i = 0; i < 3; ++i) {
      mB[i] = mstat[i * 128 + lane];
      lB[i] = mstat[i * 128 + 64 + lane];
      mS = fmaxf(mS, mB[i]);
    }
    float f0 = exp2f(m_run - mS);
    float fi[3];
    float l_tot = l_run * f0;
#pragma unroll
    for (int i = 0; i < 3; ++i) { fi[i] = exp2f(mB[i] - mS); l_tot += lB[i] * fi[i]; }
    float inv = 1.0f / l_tot;
#pragma unroll
    for (int mt = 0; mt < 2; ++mt) {
#pragma unroll
      for (int rgq = 0; rgq < 4; ++rgq) {
        s16x4 pb;
#pragma unroll
        for (int e = 0; e < 4; ++e) {
          int rg = 4 * rgq + e;
          float val = o[mt][rg] * f0;
#pragma unroll
          for (int i = 0; i < 3; ++i)
            val += obuf[i * 2048 + (mt * 16 + rg) * 64 + lane] * fi[i];
          pb[e] = (short)f2bf(val * inv);
        }
        int d0 = 32 * mt + 8 * rgq + 4 * h;
        int byte = qcol * 128 + d0 * 2;
        *(s16x4*)((char*)clds + (byte ^ swzK(qcol))) = pb;
      }
    }
  }
  __syncthreads();

  // ---- fused output projection: out[q0..q0+32) x 1024 = ctx(32x64) . Wo^T ----
  s16x8 afr[2][2];
#pragma unroll
  for (int mt = 0; mt < 2; ++mt)
#pragma unroll
    for (int kk = 0; kk < 2; ++kk) {
      int ra = 16 * mt + c;
      afr[mt][kk] = *(const s16x8*)((char*)clds +
                      ((ra * 128 + (32 * kk + 8 * g) * 2) ^ swzK(ra)));
    }
  const int wchunk = (lane & 15) * 32 + (lane >> 4) * 8;   // Wo_b frag lane offset
  const size_t orow0 = (size_t)(b * TT + q0);
#pragma unroll 4
  for (int nt = 0; nt < 16; ++nt) {
    int col = wv * 256 + 16 * nt + c;
    s16x8 bfr[2];
#pragma unroll
    for (int kk = 0; kk < 2; ++kk)
      bfr[kk] = *(const s16x8*)(Wo_b + (size_t)(wv * 16 + nt) * 1024
                                + kk * 512 + wchunk);
    f32x4 acc4[2];
#pragma unroll
    for (int mt = 0; mt < 2; ++mt)
#pragma unroll
      for (int e = 0; e < 4; ++e) acc4[mt][e] = 0.0f;
#pragma unroll
    for (int kk = 0; kk < 2; ++kk)
#pragma unroll
      for (int mt = 0; mt < 2; ++mt)
        acc4[mt] = __builtin_amdgcn_mfma_f32_16x16x32_bf16(afr[mt][kk], bfr[kk],
                                                           acc4[mt], 0, 0, 0);
    float bias = bo[col];
#pragma unroll
    for (int mt = 0; mt < 2; ++mt)
#pragma unroll
      for (int i = 0; i < 4; ++i) {
        size_t row = orow0 + 16 * mt + 4 * g + i;
        out[row * HH + col] = acc4[mt][i] + bias;
      }
  }
}

// ---------------------------------------------------------------------------
extern "C" void kernel_launch(void* const* d_in, const int* in_sizes, int n_in,
                              void* d_out, int out_size, void* d_ws, size_t ws_size,
                              hipStream_t stream)
{
  const float* y  = (const float*)d_in[0];
  const float* Wq = (const float*)d_in[1];
  const float* bq = (const float*)d_in[2];
  const float* Wk = (const float*)d_in[3];
  const float* bk = (const float*)d_in[4];
  const float* Wv = (const float*)d_in[5];
  const float* bv = (const float*)d_in[6];
  const float* Wo = (const float*)d_in[7];
  const float* bo = (const float*)d_in[8];
  float* out = (float*)d_out;
  char* ws = (char*)d_ws;
  // workspace layout (bytes) — total 6,815,744 (6.5 MiB)
  unsigned short* Wall  = (unsigned short*)(ws);                        // 384 KiB
  unsigned short* Wo_b  = (unsigned short*)(ws + 393216);               // 128 KiB
  unsigned short* q_ws  = (unsigned short*)(ws + 524288);               // 2 MiB
  unsigned short* k_ws  = (unsigned short*)(ws + 524288 + 2097152);     // 2 MiB
  unsigned short* vT_ws = (unsigned short*)(ws + 524288 + 2 * 2097152); // 2 MiB

  prep_kernel<<<dim3(256), dim3(256), 0, stream>>>(Wq, Wk, Wv, Wo, Wall, Wo_b);
  qkv_kernel<<<dim3(256), dim3(256), 0, stream>>>(y, Wall, bq, bk, bv, q_ws, k_ws, vT_ws);
  attn_kernel<<<dim3(512), dim3(256), 0, stream>>>(q_ws, k_ws, vT_ws, Wo_b, bo, out);
}